// Round 4
// baseline (3756.848 us; speedup 1.0000x reference)
//
#include <hip/hip_runtime.h>
#include <hip/hip_bf16.h>
#include <hip/hip_cooperative_groups.h>

namespace cg = cooperative_groups;

// Problem constants (reference: t1_t0=1, TOL=0.05 -> 20 SSP-RK3 steps)
#define MB     32
#define NCH    4
#define LL     2048
#define HID    64
#define KSZ    5
#define GG     10
#define RI     (LL - 2*GG)   // 2028
#define TPOS   128
#define NTILES 16
#define THR    256
#define NSTEPS 20
#define HSTEP  0.05f

__device__ __forceinline__ int pmap(int q) {
  // bdry read map: ghost -> interior source (period RI)
  if (q < GG) return q + RI;
  if (q >= LL - GG) return q - RI;
  return q;
}

// ---- verbatim round-2 stage body (weights pre-loaded by caller) ----
template<bool MAP, bool SCATTER>
__device__ __forceinline__ void stage_dev(
    const float* __restrict__ z, const float* __restrict__ cin,
    float* __restrict__ outp,
    const float* __restrict__ w1r, float b1r,
    const float (*w2s)[KSZ][HID], const float* __restrict__ b2s,
    float (*in_s)[TPOS + 8], float (*th_s)[HID],
    float ca, float cb, float cc_,
    int t, int tile, int mi)
{
  const int p0 = GG + tile * TPOS;
  const int validT = min(TPOS, (LL - GG) - p0);            // 128, last tile 108

  const float* zb   = z   + mi * (NCH * LL);
  const float* cinb = cin + mi * (NCH * LL);
  float*       outb = outp + mi * (NCH * LL);

  // ---- load conv-input tile (through map for stages 2/3; raw for stage 1) ----
  const int LOADN = validT + 8;
  for (int i = t; i < NCH * (TPOS + 8); i += THR) {
    int ci = i / (TPOS + 8);
    int j  = i - ci * (TPOS + 8);
    if (j < LOADN) {
      int q  = p0 - 4 + j;
      int qq = MAP ? pmap(q) : q;      // raw q always in [6, 2042) -> in bounds
      in_s[ci][j] = cinb[ci * LL + qq];
    }
  }
  __syncthreads();

  // ---- phase 1: hidden = tanh(conv1(input)), rows [0, validT+4) ----
  {
    const int c  = t & 63;
    const int pg = t >> 6;
    const int THN = validT + 4;
    const int j0  = pg * 35;                 // multiple of 5 -> static rotation
    const int j1  = min(THN, j0 + 35);
    float zw[NCH][KSZ];
    #pragma unroll
    for (int d = 0; d < 4; ++d) {
      #pragma unroll
      for (int ci = 0; ci < NCH; ++ci)
        zw[ci][d] = in_s[ci][j0 + d];        // slot (j0+d)%5 == d
    }
    for (int jb = j0; jb < j1; jb += 5) {
      #pragma unroll
      for (int u = 0; u < 5; ++u) {
        int j = jb + u;
        if (j < j1) {
          #pragma unroll
          for (int ci = 0; ci < NCH; ++ci)
            zw[ci][(u + 4) % 5] = in_s[ci][j + 4];
          float acc = b1r;
          #pragma unroll
          for (int ci = 0; ci < NCH; ++ci) {
            #pragma unroll
            for (int k = 0; k < KSZ; ++k)
              acc = fmaf(w1r[ci * KSZ + k], zw[ci][(u + k) % 5], acc);
          }
          float e  = __expf(2.0f * acc);     // fast tanh
          float th = 1.0f - 2.0f * __frcp_rn(e + 1.0f);
          th_s[j][(((c >> 2) ^ (j & 15)) << 2) | (c & 3)] = th;   // chunk-XOR swizzle
        }
      }
    }
  }
  __syncthreads();

  // ---- phase 2: conv2 + combine + write (+ ghost scatter for carry) ----
  {
    const int x   = t >> 1;
    const int cop = t & 1;
    if (x < validT) {
      const int co0 = cop * 2, co1 = co0 + 1;
      float a0 = b2s[co0], a1 = b2s[co1];
      const float4* w2v0 = (const float4*)&w2s[co0][0][0];
      const float4* w2v1 = (const float4*)&w2s[co1][0][0];
      #pragma unroll
      for (int k = 0; k < KSZ; ++k) {
        const int row = x + k;
        const float4* thv = (const float4*)&th_s[row][0];
        const int rs = row & 15;
        #pragma unroll
        for (int ccn = 0; ccn < 16; ++ccn) {
          float4 tv = thv[ccn ^ rs];
          float4 wa = w2v0[k * 16 + ccn];
          float4 wb = w2v1[k * 16 + ccn];
          a0 = fmaf(tv.x, wa.x, a0); a0 = fmaf(tv.y, wa.y, a0);
          a0 = fmaf(tv.z, wa.z, a0); a0 = fmaf(tv.w, wa.w, a0);
          a1 = fmaf(tv.x, wb.x, a1); a1 = fmaf(tv.y, wb.y, a1);
          a1 = fmaf(tv.z, wb.z, a1); a1 = fmaf(tv.w, wb.w, a1);
        }
      }
      const int p = p0 + x;
      float v0 = ca * zb[co0 * LL + p] + cb * cinb[co0 * LL + p] + cc_ * a0;
      float v1 = ca * zb[co1 * LL + p] + cb * cinb[co1 * LL + p] + cc_ * a1;
      outb[co0 * LL + p] = v0;
      outb[co1 * LL + p] = v1;
      if (SCATTER) {
        if (p >= LL - 2 * GG && p < LL - GG) {   // -> low ghosts [0,G)
          outb[co0 * LL + p - RI] = v0;
          outb[co1 * LL + p - RI] = v1;
        }
        if (p >= GG && p < 2 * GG) {             // -> high ghosts [L-G,L)
          outb[co0 * LL + p + RI] = v0;
          outb[co1 * LL + p + RI] = v1;
        }
      }
    }
  }
}

// ================= cooperative whole-integration kernel =================
__global__ __launch_bounds__(THR, 2)
void ode_coop(const float* __restrict__ z0, const float* __restrict__ W1g,
              const float* __restrict__ b1g, const float* __restrict__ W2g,
              const float* __restrict__ b2g, float* __restrict__ outp,
              float* zA, float* zB, float* u1p, float* u2p)
{
  cg::grid_group grid = cg::this_grid();

  __shared__ float in_s[NCH][TPOS + 8];
  __shared__ __align__(16) float th_s[TPOS + 4][HID];
  __shared__ __align__(16) float w2s[NCH][KSZ][HID];
  __shared__ float b2s[NCH];

  const int t    = threadIdx.x;
  const int tile = blockIdx.x;
  const int mi   = blockIdx.y;

  // persistent weights (loaded once for all 60 stages)
  for (int i = t; i < NCH * KSZ * HID; i += THR) {
    int co = i / (KSZ * HID); int rem = i - co * (KSZ * HID);
    int k = rem / HID; int c2 = rem - k * HID;
    w2s[co][k][c2] = W2g[(co * HID + c2) * KSZ + k];
  }
  if (t < NCH) b2s[t] = b2g[t];
  const int c = t & 63;
  float w1r[NCH * KSZ];
  #pragma unroll
  for (int i = 0; i < NCH * KSZ; ++i) w1r[i] = W1g[c * (NCH * KSZ) + i];
  const float b1r = b1g[c];
  __syncthreads();

  const float h = HSTEP;
  const float* zc = z0;
  for (int s = 0; s < NSTEPS; ++s) {
    float* znext = (s == NSTEPS - 1) ? outp : ((s & 1) ? zB : zA);
    stage_dev<false, false>(zc, zc, u1p, w1r, b1r, w2s, b2s, in_s, th_s,
                            1.0f, 0.0f, h, t, tile, mi);
    grid.sync();
    stage_dev<true, false>(zc, u1p, u2p, w1r, b1r, w2s, b2s, in_s, th_s,
                           0.75f, 0.25f, 0.25f * h, t, tile, mi);
    grid.sync();
    stage_dev<true, true>(zc, u2p, znext, w1r, b1r, w2s, b2s, in_s, th_s,
                          1.0f / 3.0f, 2.0f / 3.0f, 2.0f * h / 3.0f, t, tile, mi);
    grid.sync();
    zc = znext;
  }
}

// ================= fallback: proven round-2 per-stage kernel =================
template<bool MAP, bool SCATTER>
__global__ __launch_bounds__(THR, 2)
void stage_kernel(const float* __restrict__ z, const float* __restrict__ cin,
                  float* __restrict__ outp,
                  const float* __restrict__ W1g, const float* __restrict__ b1g,
                  const float* __restrict__ W2g, const float* __restrict__ b2g,
                  float ca, float cb, float cc_)
{
  __shared__ float in_s[NCH][TPOS + 8];
  __shared__ __align__(16) float th_s[TPOS + 4][HID];
  __shared__ __align__(16) float w2s[NCH][KSZ][HID];
  __shared__ float b2s[NCH];

  const int t    = threadIdx.x;
  const int tile = blockIdx.x;
  const int mi   = blockIdx.y;

  for (int i = t; i < NCH * KSZ * HID; i += THR) {
    int co = i / (KSZ * HID); int rem = i - co * (KSZ * HID);
    int k = rem / HID; int c2 = rem - k * HID;
    w2s[co][k][c2] = W2g[(co * HID + c2) * KSZ + k];
  }
  if (t < NCH) b2s[t] = b2g[t];
  const int c = t & 63;
  float w1r[NCH * KSZ];
  #pragma unroll
  for (int i = 0; i < NCH * KSZ; ++i) w1r[i] = W1g[c * (NCH * KSZ) + i];
  const float b1r = b1g[c];
  // NOTE: no explicit sync needed here; stage_dev syncs after its in_s load,
  // which also covers w2s/b2s visibility.
  stage_dev<MAP, SCATTER>(z, cin, outp, w1r, b1r, w2s, b2s, in_s, th_s,
                          ca, cb, cc_, t, tile, mi);
}

extern "C" void kernel_launch(void* const* d_in, const int* in_sizes, int n_in,
                              void* d_out, int out_size, void* d_ws, size_t ws_size,
                              hipStream_t stream) {
  const float* z0 = (const float*)d_in[0];
  const float* W1 = (const float*)d_in[1];
  const float* b1 = (const float*)d_in[2];
  const float* W2 = (const float*)d_in[3];
  const float* b2 = (const float*)d_in[4];
  float* out = (float*)d_out;

  const size_t ELEMS = (size_t)MB * NCH * LL;  // 262144 floats = 1 MiB
  float* zA  = (float*)d_ws;
  float* zB  = zA + ELEMS;
  float* u1p = zB + ELEMS;
  float* u2p = u1p + ELEMS;

  dim3 grid(NTILES, MB);
  dim3 block(THR);

  void* args[] = { (void*)&z0, (void*)&W1, (void*)&b1, (void*)&W2, (void*)&b2,
                   (void*)&out, (void*)&zA, (void*)&zB, (void*)&u1p, (void*)&u2p };
  hipError_t err = hipLaunchCooperativeKernel((const void*)ode_coop, grid, block,
                                              args, 0, stream);
  if (err != hipSuccess) {
    (void)hipGetLastError();   // clear sticky error, run proven multi-launch path
    const float h = HSTEP;
    const float* zc = z0;
    for (int s = 0; s < NSTEPS; ++s) {
      float* znext = (s == NSTEPS - 1) ? out : ((s & 1) ? zB : zA);
      stage_kernel<false, false><<<grid, block, 0, stream>>>(
          zc, zc, u1p, W1, b1, W2, b2, 1.0f, 0.0f, h);
      stage_kernel<true, false><<<grid, block, 0, stream>>>(
          zc, u1p, u2p, W1, b1, W2, b2, 0.75f, 0.25f, 0.25f * h);
      stage_kernel<true, true><<<grid, block, 0, stream>>>(
          zc, u2p, znext, W1, b1, W2, b2, 1.0f / 3.0f, 2.0f / 3.0f, 2.0f * h / 3.0f);
      zc = znext;
    }
  }
}